// Round 1
// baseline (166.474 us; speedup 1.0000x reference)
//
#include <hip/hip_runtime.h>

// SurfNetwork: grid-hash gather + tiny MLP + transmittance cumprod + rgb reduce.
// One 128-thread block per batch row b. Thread n handles sample n.
//
// Reference layout notes:
//   feat[b,2n]   = gridWeight[x[b,n,0]]   (float4 row)
//   feat[b,2n+1] = gridWeight[x[b,n,1]]
//   sigma[b,n]   = sigmoid(feat[b,2n,0] * feat[b,2n+1,0])
//   geo[b,n,0:6] = {feat[b,2n,1:4], feat[b,2n+1,1:4]}
//   h = [d[b,0:16], geo]  (22) -> relu(h@W0) (8) -> sigmoid(@W1) (3)
//   T[n] = prod_{k<n}(1-sigma[k]);  w = T*sigma;  rgb = sum_n w*color
//
// d[b]@W0[0:16,:] is sample-invariant -> precomputed once per block (dW0[8]).

__global__ __launch_bounds__(128) void surf_kernel(
    const int*   __restrict__ x,      // [B, N, 2]
    const float* __restrict__ dvec,   // [B, 16]
    const float* __restrict__ grid,   // [TABLE, 4]
    const float* __restrict__ W0,     // [22, 8] row-major
    const float* __restrict__ W1,     // [8, 3]  row-major
    float*       __restrict__ sigma_out, // [B, N]
    float*       __restrict__ rgb_out,   // [B, 3]
    int N)
{
    const int b    = blockIdx.x;
    const int n    = threadIdx.x;  // 0..127
    const int lane = n & 63;
    const int wv   = n >> 6;

    __shared__ float W0s[22 * 8];
    __shared__ float W1s[8 * 3];
    __shared__ float dsh[16];
    __shared__ float dW0[8];
    __shared__ float scanb[128];
    __shared__ float wtot[2];
    __shared__ float rsum[2][3];

    // Stage weights + d[b] into LDS.
    if (n < 88) { W0s[n] = W0[n]; W0s[n + 88] = W0[n + 88]; }
    if (n < 24) W1s[n] = W1[n];
    if (n < 16) dsh[n] = dvec[(size_t)b * 16 + n];
    __syncthreads();

    // Sample-invariant part of the first linear layer.
    if (n < 8) {
        float acc = 0.f;
        #pragma unroll
        for (int i = 0; i < 16; ++i) acc += dsh[i] * W0s[i * 8 + n];
        dW0[n] = acc;
    }

    // Gather the two grid rows for this sample (random 16B reads).
    const int2 idx = ((const int2*)x)[(size_t)b * N + n];
    const float4 fa = ((const float4*)grid)[idx.x];
    const float4 fb = ((const float4*)grid)[idx.y];

    const float s = 1.f / (1.f + __expf(-(fa.x * fb.x)));
    const float geo[6] = { fa.y, fa.z, fa.w, fb.y, fb.z, fb.w };

    __syncthreads();  // dW0 ready

    // MLP: h8 = relu(dW0 + geo@W0[16:22,:]); col = sigmoid(h8@W1)
    float h8[8];
    #pragma unroll
    for (int j = 0; j < 8; ++j) {
        float acc = dW0[j];
        #pragma unroll
        for (int i = 0; i < 6; ++i) acc += geo[i] * W0s[(16 + i) * 8 + j];
        h8[j] = fmaxf(acc, 0.f);
    }
    float col[3];
    #pragma unroll
    for (int c = 0; c < 3; ++c) {
        float acc = 0.f;
        #pragma unroll
        for (int k = 0; k < 8; ++k) acc += h8[k] * W1s[k * 3 + c];
        col[c] = 1.f / (1.f + __expf(-acc));
    }

    // Inclusive product scan of (1 - s) across the 128 threads.
    float p = 1.f - s;
    #pragma unroll
    for (int off = 1; off < 64; off <<= 1) {
        float o = __shfl_up(p, off, 64);
        if (lane >= off) p *= o;
    }
    if (lane == 63) wtot[wv] = p;
    __syncthreads();
    if (wv == 1) p *= wtot[0];
    scanb[n] = p;
    __syncthreads();

    // Exclusive (shifted) scan = transmittance T; w = T * sigma.
    const float T = (n == 0) ? 1.f : scanb[n - 1];
    const float w = T * s;

    sigma_out[(size_t)b * N + n] = s;

    // Reduce w*col over the block -> rgb[b].
    float r0 = w * col[0], r1 = w * col[1], r2 = w * col[2];
    #pragma unroll
    for (int off = 32; off > 0; off >>= 1) {
        r0 += __shfl_down(r0, off, 64);
        r1 += __shfl_down(r1, off, 64);
        r2 += __shfl_down(r2, off, 64);
    }
    if (lane == 0) { rsum[wv][0] = r0; rsum[wv][1] = r1; rsum[wv][2] = r2; }
    __syncthreads();
    if (n == 0) {
        rgb_out[b * 3 + 0] = rsum[0][0] + rsum[1][0];
        rgb_out[b * 3 + 1] = rsum[0][1] + rsum[1][1];
        rgb_out[b * 3 + 2] = rsum[0][2] + rsum[1][2];
    }
}

extern "C" void kernel_launch(void* const* d_in, const int* in_sizes, int n_in,
                              void* d_out, int out_size, void* d_ws, size_t ws_size,
                              hipStream_t stream) {
    const int*   x    = (const int*)d_in[0];
    const float* dvec = (const float*)d_in[1];
    const float* grid = (const float*)d_in[2];
    const float* W0   = (const float*)d_in[3];
    const float* W1   = (const float*)d_in[4];

    const int B = in_sizes[1] / 16;          // d is [B, 16]
    const int N = in_sizes[0] / (2 * B);     // x is [B, N, 2]; N = 128

    float* sigma_out = (float*)d_out;                 // [B, N]
    float* rgb_out   = sigma_out + (size_t)B * N;     // [B, 3]

    surf_kernel<<<B, N, 0, stream>>>(x, dvec, grid, W0, W1, sigma_out, rgb_out, N);
}